// Round 6
// baseline (1587.272 us; speedup 1.0000x reference)
//
#include <hip/hip_runtime.h>
#include <math.h>

#define BB 32
#define MM 2048
#define KK 4
#define EE 128
#define GG 128
#define VV 50000
#define HOPS 3
#define NT 391    // ceil(VV/128) v-tiles

// Two-level grid barrier state. Zero-initialized at module load and
// self-restoring across calls (counters return to 0, gen grows), so it is
// safe under graph replay with no per-call memset.
__device__ int g_bar[2080];   // [0]=gen, [32]=main cnt, [64 + s*32]=sub cnt s

struct Args {
    const int*   ctx;
    const float* hprev;
    const int*   y;
    const float* emb;
    const float* W_ih;
    const float* W_hh;
    const float* b_ih;
    const float* b_hh;
    const float* Wv;
    const float* bv;
    float* out_h;
    float* out_pv;
    float* out_attn;
    float* q0;      // [B][E]
    float* part;    // [B][8][2]
    float* d;       // [B][V]
    float* w0;      // [B][V] hop0 scattered attention weights
    float* w1;      // [B][V] hop1
    float* o_acc0;  // [B][E] o from hop 0 (== o1)
    float* o_acc1;  // [B][E] o from hop 1
    int nb;
};

__device__ __forceinline__ void gbar(int nb) {
    __threadfence();                       // release: drain stores + L2 writeback
    __syncthreads();
    if (threadIdx.x == 0) {
        int* gen = g_bar;
        int* mc  = g_bar + 32;
        int  g   = __hip_atomic_load(gen, __ATOMIC_RELAXED, __HIP_MEMORY_SCOPE_AGENT);
        int  sub = blockIdx.x & 63;
        int* sc  = g_bar + 64 + sub*32;
        int  spb = nb >> 6;                // blocks per sub-counter (nb multiple of 64)
        bool release = false;
        if (__hip_atomic_fetch_add(sc, 1, __ATOMIC_ACQ_REL, __HIP_MEMORY_SCOPE_AGENT) == spb - 1) {
            __hip_atomic_store(sc, 0, __ATOMIC_RELAXED, __HIP_MEMORY_SCOPE_AGENT);
            if (__hip_atomic_fetch_add(mc, 1, __ATOMIC_ACQ_REL, __HIP_MEMORY_SCOPE_AGENT) == 63) {
                __hip_atomic_store(mc, 0, __ATOMIC_RELAXED, __HIP_MEMORY_SCOPE_AGENT);
                __hip_atomic_fetch_add(gen, 1, __ATOMIC_RELEASE, __HIP_MEMORY_SCOPE_AGENT);
                release = true;
            }
        }
        if (!release) {
            while (__hip_atomic_load(gen, __ATOMIC_ACQUIRE, __HIP_MEMORY_SCOPE_AGENT) == g)
                __builtin_amdgcn_s_sleep(8);
        }
    }
    __syncthreads();
    __threadfence();                       // acquire: invalidate L1/L2 before reads
}

__global__ __launch_bounds__(256, 2) void fused_kernel(Args a) {
    const int blk  = blockIdx.x;
    const int t    = threadIdx.x;
    const int nb   = a.nb;
    const int lane = t & 63;
    const int wvid = t >> 6;

    __shared__ __align__(16) float smem[12352];   // 49.4 KB, aliased per phase

    // ================= P0: GRU (blocks 0..31) + zero w0,w1,o_acc0,o_acc1 ============
    if (blk < BB) {
        int b = blk;
        float* x  = smem;          // 128
        float* hh = smem + 128;    // 128
        float* gi = smem + 256;    // 384
        float* gh = smem + 640;    // 384
        if (t < EE)          x[t]     = a.emb[(size_t)a.y[b]*EE + t];
        else if (t < 2*EE)   hh[t-EE] = a.hprev[b*GG + (t-EE)];
        __syncthreads();
        for (int g = t; g < 3*GG; g += 256) {
            float accI = a.b_ih[g], accH = a.b_hh[g];
            const float* wi = a.W_ih + (size_t)g*EE;
            const float* wh = a.W_hh + (size_t)g*GG;
            #pragma unroll 8
            for (int e = 0; e < EE; e++) { accI += x[e]*wi[e]; accH += hh[e]*wh[e]; }
            gi[g] = accI; gh[g] = accH;
        }
        __syncthreads();
        if (t < GG) {
            float r = 1.f/(1.f + __expf(-(gi[t]      + gh[t])));
            float z = 1.f/(1.f + __expf(-(gi[GG+t]   + gh[GG+t])));
            float n = tanhf(gi[2*GG+t] + r*gh[2*GG+t]);
            float hn = (1.f - z)*n + z*hh[t];
            a.out_h[b*GG + t] = hn;
            a.q0[b*GG + t]    = hn;
        }
    } else {
        // zero w0,w1,o_acc0,o_acc1 (contiguous region starting at w0)
        const int total4 = (2*BB*VV + 2*BB*EE)/4;
        float4* wz = (float4*)a.w0;
        for (int i = (blk-BB)*256 + t; i < total4; i += (nb-BB)*256)
            wz[i] = make_float4(0.f,0.f,0.f,0.f);
    }
    gbar(nb);

    // ================= hops =================
    for (int hop = 0; hop < HOPS; hop++) {
        const int last = (hop == HOPS-1);

        // ---- P1: d[b][v] = q_hop[b] . T[v]  (wave-uniform skinny GEMM) ----
        {
            const float* T = a.emb + (size_t)hop*VV*EE;
            float* Us = smem;          // [128][32]
            float* Wt = smem + 4096;   // [32][130]
            for (int tile = blk; tile < NT; tile += nb) {
                __syncthreads();   // guard Us restage vs previous tile's readers
                for (int i = t; i < 128*32; i += 256) {
                    int e = i >> 5, b = i & 31;
                    float qv = a.q0[b*EE + e];
                    if (hop >= 1) qv += a.o_acc0[b*EE + e];
                    if (hop >= 2) qv += a.o_acc1[b*EE + e];
                    Us[i] = qv;
                }
                int v0 = tile * 128;
                float acc[2][8];
                #pragma unroll
                for (int i = 0; i < 2; i++)
                    #pragma unroll
                    for (int j = 0; j < 8; j++) acc[i][j] = 0.f;

                for (int ec = 0; ec < 128; ec += 32) {
                    __syncthreads();
                    #pragma unroll
                    for (int j = 0; j < 4; j++) {
                        int f = t + j*256;
                        int row = f >> 3, c4 = f & 7;
                        float4 w4 = make_float4(0.f,0.f,0.f,0.f);
                        if (v0 + row < VV) w4 = *(const float4*)(T + (size_t)(v0+row)*EE + ec + c4*4);
                        Wt[(c4*4+0)*130 + row] = w4.x;
                        Wt[(c4*4+1)*130 + row] = w4.y;
                        Wt[(c4*4+2)*130 + row] = w4.z;
                        Wt[(c4*4+3)*130 + row] = w4.w;
                    }
                    __syncthreads();
                    #pragma unroll 8
                    for (int e = 0; e < 32; e++) {
                        float2 w2 = *(const float2*)(Wt + e*130 + lane*2);
                        float4 ua = *(const float4*)(Us + (ec+e)*32 + wvid*8);
                        float4 ub = *(const float4*)(Us + (ec+e)*32 + wvid*8 + 4);
                        acc[0][0] += w2.x*ua.x; acc[1][0] += w2.y*ua.x;
                        acc[0][1] += w2.x*ua.y; acc[1][1] += w2.y*ua.y;
                        acc[0][2] += w2.x*ua.z; acc[1][2] += w2.y*ua.z;
                        acc[0][3] += w2.x*ua.w; acc[1][3] += w2.y*ua.w;
                        acc[0][4] += w2.x*ub.x; acc[1][4] += w2.y*ub.x;
                        acc[0][5] += w2.x*ub.y; acc[1][5] += w2.y*ub.y;
                        acc[0][6] += w2.x*ub.z; acc[1][6] += w2.y*ub.z;
                        acc[0][7] += w2.x*ub.w; acc[1][7] += w2.y*ub.w;
                    }
                }
                int v = v0 + lane*2;
                if (v < VV) {
                    #pragma unroll
                    for (int j = 0; j < 8; j++) {
                        float2 r; r.x = acc[0][j]; r.y = acc[1][j];
                        *(float2*)(a.d + (size_t)(wvid*8 + j)*VV + v) = r;
                    }
                }
            }
        }
        gbar(nb);

        // ---- P2: gather + softmax over M + scatter/output (blocks 0..31) ----
        if (blk < BB) {
            int b = blk;
            const float* db = a.d + (size_t)b*VV;
            const int4* cb  = (const int4*)a.ctx + b*MM;
            float pv[8];
            float mx = -INFINITY;
            #pragma unroll
            for (int i = 0; i < 8; i++) {
                int4 c = cb[t + i*256];
                pv[i] = db[c.x] + db[c.y] + db[c.z] + db[c.w];
                mx = fmaxf(mx, pv[i]);
            }
            float* red = smem;
            #pragma unroll
            for (int off = 32; off; off >>= 1) mx = fmaxf(mx, __shfl_down(mx, off));
            if (lane == 0) red[wvid] = mx;
            __syncthreads();
            if (t == 0) red[4] = fmaxf(fmaxf(red[0],red[1]), fmaxf(red[2],red[3]));
            __syncthreads();
            mx = red[4];
            float sum = 0.f;
            #pragma unroll
            for (int i = 0; i < 8; i++) { pv[i] = __expf(pv[i] - mx); sum += pv[i]; }
            #pragma unroll
            for (int off = 32; off; off >>= 1) sum += __shfl_down(sum, off);
            if (lane == 0) red[8 + wvid] = sum;
            __syncthreads();
            if (t == 0) red[13] = 1.f / (red[8]+red[9]+red[10]+red[11]);
            __syncthreads();
            float rs = red[13];
            if (last) {
                #pragma unroll
                for (int i = 0; i < 8; i++)
                    a.out_attn[b*MM + t + i*256] = pv[i]*rs;
            } else {
                float* wb = (hop == 0 ? a.w0 : a.w1) + (size_t)b*VV;
                #pragma unroll
                for (int i = 0; i < 8; i++) {
                    float av = pv[i]*rs;
                    int4 c = cb[t + i*256];
                    atomicAdd(wb + c.x, av);
                    atomicAdd(wb + c.y, av);
                    atomicAdd(wb + c.z, av);
                    atomicAdd(wb + c.w, av);
                }
            }
        }
        gbar(nb);

        // ---- P3: o_acc[hop][b][e] += sum_v w[b][v] * T2[v][e] ----
        if (!last) {
            const float* T2 = a.emb + (size_t)(hop+1)*VV*EE;
            const float* wv = (hop == 0) ? a.w0 : a.w1;
            float* oacc     = (hop == 0) ? a.o_acc0 : a.o_acc1;
            float* embS = smem;          // [64][128]
            float* wS   = smem + 8192;   // [64][32]
            float av[8][2];
            #pragma unroll
            for (int j = 0; j < 8; j++) { av[j][0] = 0.f; av[j][1] = 0.f; }
            for (int chunk = blk; chunk < NT; chunk += nb) {
                int v0 = chunk*128, vend = min(v0+128, VV);
                for (int vs = v0; vs < vend; vs += 64) {
                    int nv = vend - vs; if (nv > 64) nv = 64;
                    __syncthreads();
                    for (int i = t; i < 64*32; i += 256) {
                        int row = i >> 5, c4 = i & 31;
                        float4 val = make_float4(0.f,0.f,0.f,0.f);
                        if (row < nv) val = *(const float4*)(T2 + (size_t)(vs+row)*EE + c4*4);
                        *(float4*)(embS + row*128 + c4*4) = val;
                    }
                    for (int i = t; i < 512; i += 256) {
                        int b = i >> 4, vv4 = (i & 15)*4;
                        float4 val = make_float4(0.f,0.f,0.f,0.f);
                        if (vv4 < nv) val = *(const float4*)(wv + (size_t)b*VV + vs + vv4);
                        wS[(vv4+0)*32 + b] = val.x;
                        wS[(vv4+1)*32 + b] = val.y;
                        wS[(vv4+2)*32 + b] = val.z;
                        wS[(vv4+3)*32 + b] = val.w;
                    }
                    __syncthreads();
                    for (int vv = 0; vv < nv; vv++) {
                        float2 ev = *(const float2*)(embS + vv*128 + lane*2);
                        float4 w0v = *(const float4*)(wS + vv*32 + wvid*8);
                        float4 w1v = *(const float4*)(wS + vv*32 + wvid*8 + 4);
                        av[0][0] += w0v.x*ev.x; av[0][1] += w0v.x*ev.y;
                        av[1][0] += w0v.y*ev.x; av[1][1] += w0v.y*ev.y;
                        av[2][0] += w0v.z*ev.x; av[2][1] += w0v.z*ev.y;
                        av[3][0] += w0v.w*ev.x; av[3][1] += w0v.w*ev.y;
                        av[4][0] += w1v.x*ev.x; av[4][1] += w1v.x*ev.y;
                        av[5][0] += w1v.y*ev.x; av[5][1] += w1v.y*ev.y;
                        av[6][0] += w1v.z*ev.x; av[6][1] += w1v.z*ev.y;
                        av[7][0] += w1v.w*ev.x; av[7][1] += w1v.w*ev.y;
                    }
                }
            }
            if (blk < NT) {
                #pragma unroll
                for (int j = 0; j < 8; j++) {
                    atomicAdd(oacc + (wvid*8+j)*EE + lane*2,     av[j][0]);
                    atomicAdd(oacc + (wvid*8+j)*EE + lane*2 + 1, av[j][1]);
                }
            }
            gbar(nb);
        }
    }

    // ================= P4: vocab logits (K=256 wave-uniform GEMM) =================
    {
        float* Us = smem;          // [256][32]
        float* Wt = smem + 8192;   // [32][130]
        for (int tile = blk; tile < NT; tile += nb) {
            __syncthreads();
            for (int i = t; i < 256*32; i += 256) {
                int e = i >> 5, b = i & 31;
                Us[i] = (e < GG) ? a.q0[b*GG + e] : a.o_acc0[b*EE + (e - GG)];
            }
            int v0 = tile * 128;
            float acc[2][8];
            #pragma unroll
            for (int i = 0; i < 2; i++)
                #pragma unroll
                for (int j = 0; j < 8; j++) acc[i][j] = 0.f;

            for (int ec = 0; ec < 256; ec += 32) {
                __syncthreads();
                #pragma unroll
                for (int j = 0; j < 4; j++) {
                    int f = t + j*256;
                    int row = f >> 3, c4 = f & 7;
                    float4 w4 = make_float4(0.f,0.f,0.f,0.f);
                    if (v0 + row < VV) w4 = *(const float4*)(a.Wv + (size_t)(v0+row)*256 + ec + c4*4);
                    Wt[(c4*4+0)*130 + row] = w4.x;
                    Wt[(c4*4+1)*130 + row] = w4.y;
                    Wt[(c4*4+2)*130 + row] = w4.z;
                    Wt[(c4*4+3)*130 + row] = w4.w;
                }
                __syncthreads();
                #pragma unroll 8
                for (int e = 0; e < 32; e++) {
                    float2 w2 = *(const float2*)(Wt + e*130 + lane*2);
                    float4 ua = *(const float4*)(Us + (ec+e)*32 + wvid*8);
                    float4 ub = *(const float4*)(Us + (ec+e)*32 + wvid*8 + 4);
                    acc[0][0] += w2.x*ua.x; acc[1][0] += w2.y*ua.x;
                    acc[0][1] += w2.x*ua.y; acc[1][1] += w2.y*ua.y;
                    acc[0][2] += w2.x*ua.z; acc[1][2] += w2.y*ua.z;
                    acc[0][3] += w2.x*ua.w; acc[1][3] += w2.y*ua.w;
                    acc[0][4] += w2.x*ub.x; acc[1][4] += w2.y*ub.x;
                    acc[0][5] += w2.x*ub.y; acc[1][5] += w2.y*ub.y;
                    acc[0][6] += w2.x*ub.z; acc[1][6] += w2.y*ub.z;
                    acc[0][7] += w2.x*ub.w; acc[1][7] += w2.y*ub.w;
                }
            }
            int v = v0 + lane*2;
            if (v < VV) {
                float2 bb2 = *(const float2*)(a.bv + v);
                #pragma unroll
                for (int j = 0; j < 8; j++) {
                    float2 r; r.x = acc[0][j] + bb2.x; r.y = acc[1][j] + bb2.y;
                    *(float2*)(a.out_pv + (size_t)(wvid*8 + j)*VV + v) = r;
                }
            }
        }
    }
    gbar(nb);

    // ================= P5: vocab softmax partials (blocks 0..255) =================
    if (blk < 256) {
        int b = blk >> 3, c = blk & 7;
        const float* row = a.out_pv + (size_t)b*VV;
        int start = c*6250, end = min(start + 6250, VV);
        float* red = smem;
        float mx = -INFINITY;
        for (int i = start + t; i < end; i += 256) mx = fmaxf(mx, row[i]);
        #pragma unroll
        for (int off = 32; off; off >>= 1) mx = fmaxf(mx, __shfl_down(mx, off));
        if (lane == 0) red[wvid] = mx;
        __syncthreads();
        float m = fmaxf(fmaxf(red[0], red[1]), fmaxf(red[2], red[3]));
        float sum = 0.f;
        for (int i = start + t; i < end; i += 256) sum += __expf(row[i] - m);
        #pragma unroll
        for (int off = 32; off; off >>= 1) sum += __shfl_down(sum, off);
        __syncthreads();
        if (lane == 0) red[8 + wvid] = sum;
        __syncthreads();
        if (t == 0) {
            a.part[blk*2]   = m;
            a.part[blk*2+1] = red[8]+red[9]+red[10]+red[11];
        }
    }
    gbar(nb);

    // ================= P6: finalize p_vocab in place =================
    {
        float* Ms = smem;        // [32]
        float* Rs = smem + 32;   // [32]
        if (t < BB) {
            const float* pp = a.part + t*16;
            float M = -INFINITY;
            #pragma unroll
            for (int c = 0; c < 8; c++) M = fmaxf(M, pp[c*2]);
            float S = 0.f;
            #pragma unroll
            for (int c = 0; c < 8; c++) S += pp[c*2+1] * __expf(pp[c*2] - M);
            Ms[t] = M; Rs[t] = 1.f / S;
        }
        __syncthreads();
        const int total = BB*VV;
        for (int i = blk*256 + t; i < total; i += nb*256) {
            int b = i / VV;
            a.out_pv[i] = __expf(a.out_pv[i] - Ms[b]) * Rs[b];
        }
    }
}

extern "C" void kernel_launch(void* const* d_in, const int* in_sizes, int n_in,
                              void* d_out, int out_size, void* d_ws, size_t ws_size,
                              hipStream_t stream) {
    Args a;
    a.ctx   = (const int*)  d_in[0];
    a.hprev = (const float*)d_in[1];
    a.y     = (const int*)  d_in[2];
    a.emb   = (const float*)d_in[3];
    a.W_ih  = (const float*)d_in[4];
    a.W_hh  = (const float*)d_in[5];
    a.b_ih  = (const float*)d_in[6];
    a.b_hh  = (const float*)d_in[7];
    a.Wv    = (const float*)d_in[8];
    a.bv    = (const float*)d_in[9];

    float* out  = (float*)d_out;
    a.out_h     = out;                        // [B][G]
    a.out_pv    = out + BB*GG;                // [B][V]
    a.out_attn  = a.out_pv + (size_t)BB*VV;   // [B][M]

    float* ws = (float*)d_ws;
    a.q0     = ws;                            // 4096
    a.part   = a.q0 + BB*EE;                  // 512
    a.d      = a.part + 512;                  // B*V
    a.w0     = a.d + (size_t)BB*VV;           // B*V  (w0,w1,o_acc0,o_acc1 contiguous)
    a.w1     = a.w0 + (size_t)BB*VV;          // B*V
    a.o_acc0 = a.w1 + (size_t)BB*VV;          // 4096
    a.o_acc1 = a.o_acc0 + BB*EE;              // 4096

    int maxb = 0;
    int nb = 512;
    if (hipOccupancyMaxActiveBlocksPerMultiprocessor(&maxb, (const void*)fused_kernel, 256, 0) == hipSuccess
        && maxb >= 1) {
        nb = maxb * 256;
        if (nb > 512) nb = 512;
        if (nb < 256) nb = 256;   // phases require >= 256 blocks
    }
    a.nb = nb;

    void* params[] = { (void*)&a };
    hipLaunchCooperativeKernel((const void*)fused_kernel, dim3(nb), dim3(256),
                               params, 0, stream);
}

// Round 7
// 500.924 us; speedup vs baseline: 3.1687x; 3.1687x over previous
//
#include <hip/hip_runtime.h>
#include <math.h>

#define BB 32
#define MM 2048
#define KK 4
#define EE 128
#define GG 128
#define VV 50000
#define HOPS 3

// ============ GRU (blocks 0..31) + zero w0,w1 (blocks 32..287) ============
__global__ __launch_bounds__(256) void gru_zero_kernel(
    const float* __restrict__ emb0, const int* __restrict__ y,
    const float* __restrict__ hprev,
    const float* __restrict__ W_ih, const float* __restrict__ W_hh,
    const float* __restrict__ b_ih, const float* __restrict__ b_hh,
    float* __restrict__ h_out, float* __restrict__ q0,
    float* __restrict__ wz)            // w0,w1 contiguous: 2*B*V floats
{
    int blk = blockIdx.x, t = threadIdx.x;
    if (blk < BB) {
        int b = blk;
        __shared__ float x[EE], hh[GG], gi[3*GG], gh[3*GG];
        if (t < EE)          x[t]     = emb0[(size_t)y[b]*EE + t];
        else if (t < 2*EE)   hh[t-EE] = hprev[b*GG + (t-EE)];
        __syncthreads();
        for (int g = t; g < 3*GG; g += 256) {
            float accI = b_ih[g], accH = b_hh[g];
            const float* wi = W_ih + (size_t)g*EE;
            const float* wh = W_hh + (size_t)g*GG;
            #pragma unroll 8
            for (int e = 0; e < EE; e++) { accI += x[e]*wi[e]; accH += hh[e]*wh[e]; }
            gi[g] = accI; gh[g] = accH;
        }
        __syncthreads();
        if (t < GG) {
            float r = 1.f/(1.f + __expf(-(gi[t]      + gh[t])));
            float z = 1.f/(1.f + __expf(-(gi[GG+t]   + gh[GG+t])));
            float n = tanhf(gi[2*GG+t] + r*gh[2*GG+t]);
            float hn = (1.f - z)*n + z*hh[t];
            h_out[b*GG + t] = hn;
            q0[b*GG + t]    = hn;
        }
    } else {
        const int total4 = (2*BB*VV)/4;
        float4* wp = (float4*)wz;
        for (int i = (blk-BB)*256 + t; i < total4; i += 256*256)
            wp[i] = make_float4(0.f,0.f,0.f,0.f);
    }
}

// ============ d[b][v] = q[b] . T[v]   thread-owns-row, no inner syncs ============
// block = 256 (4 waves); wave = b-group of 8; thread's row v = blk*64 + lane.
// q staged once as q2[c][b][j] (c = e>>2, j = e&3) so a b-group's chunk is
// 8 consecutive float4s -> wave-uniform ds_read_b128 broadcast (free).
__global__ __launch_bounds__(256) void dvec_kernel(
    const float* __restrict__ q0, const float* __restrict__ oa0,
    const float* __restrict__ oa1, int hop,
    const float* __restrict__ W, float* __restrict__ d)
{
    __shared__ float q2[4096];   // 16 KB
    int t = threadIdx.x;
    for (int i = t; i < 4096; i += 256) {
        int e = i >> 5, b = i & 31;
        float v = q0[b*EE + e];
        if (hop >= 1) v += oa0[b*EE + e];
        if (hop >= 2) v += oa1[b*EE + e];
        q2[(e >> 2)*128 + b*4 + (e & 3)] = v;
    }
    __syncthreads();
    int lane = t & 63, bg = t >> 6;
    int v = blockIdx.x*64 + lane;
    const float4* row = (const float4*)(W + (size_t)(v < VV ? v : VV-1)*EE);
    float acc[8];
    #pragma unroll
    for (int k = 0; k < 8; k++) acc[k] = 0.f;
    #pragma unroll 4
    for (int c = 0; c < 32; c++) {
        float4 wv = row[c];
        const float4* uq = (const float4*)(q2 + c*128 + bg*32);
        #pragma unroll
        for (int k = 0; k < 8; k++) {
            float4 u = uq[k];
            acc[k] += wv.x*u.x + wv.y*u.y + wv.z*u.z + wv.w*u.w;
        }
    }
    if (v < VV) {
        #pragma unroll
        for (int k = 0; k < 8; k++)
            d[(size_t)(bg*8 + k)*VV + v] = acc[k];
    }
}

// ============ p[b,m] = sum_k d[b][ctx[b,m,k]] ============
__global__ __launch_bounds__(256) void pgather_kernel(
    const float* __restrict__ d, const int* __restrict__ ctx,
    float* __restrict__ p)
{
    int gid = blockIdx.x*256 + threadIdx.x;   // over B*M = 65536
    int b = gid >> 11;
    const int4 c = *(const int4*)(ctx + (size_t)gid*KK);
    const float* db = d + (size_t)b*VV;
    p[gid] = db[c.x] + db[c.y] + db[c.z] + db[c.w];
}

// ============ softmax over M, then scatter to w[b][v] (or write out_attn) ======
__global__ __launch_bounds__(256) void softmax_sc_kernel(
    const float* __restrict__ p, const int* __restrict__ ctx,
    float* __restrict__ w,               // scatter dest (mode 0)
    float* __restrict__ out_attn,        // output dest (mode 1)
    int mode)
{
    int b = blockIdx.x, t = threadIdx.x;
    const float* row = p + (size_t)b*MM;
    float pv[8];
    float mx = -INFINITY;
    #pragma unroll
    for (int i = 0; i < 8; i++) { pv[i] = row[t + i*256]; mx = fmaxf(mx, pv[i]); }
    __shared__ float red[16];
    int wv = t >> 6, lane = t & 63;
    #pragma unroll
    for (int off = 32; off; off >>= 1) mx = fmaxf(mx, __shfl_down(mx, off));
    if (lane == 0) red[wv] = mx;
    __syncthreads();
    if (t == 0) red[4] = fmaxf(fmaxf(red[0],red[1]), fmaxf(red[2],red[3]));
    __syncthreads();
    mx = red[4];
    float sum = 0.f;
    #pragma unroll
    for (int i = 0; i < 8; i++) { pv[i] = __expf(pv[i] - mx); sum += pv[i]; }
    #pragma unroll
    for (int off = 32; off; off >>= 1) sum += __shfl_down(sum, off);
    if (lane == 0) red[8 + wv] = sum;
    __syncthreads();
    if (t == 0) red[13] = 1.f / (red[8]+red[9]+red[10]+red[11]);
    __syncthreads();
    float rs = red[13];
    if (mode) {
        #pragma unroll
        for (int i = 0; i < 8; i++)
            out_attn[b*MM + t + i*256] = pv[i]*rs;
    } else {
        float* wb = w + (size_t)b*VV;
        const int4* cb = (const int4*)ctx + b*MM;
        #pragma unroll
        for (int i = 0; i < 8; i++) {
            float av = pv[i]*rs;
            int4 c = cb[t + i*256];
            atomicAdd(wb + c.x, av);
            atomicAdd(wb + c.y, av);
            atomicAdd(wb + c.z, av);
            atomicAdd(wb + c.w, av);
        }
    }
}

// ============ o_part[chunk][b][e] = sum_{v in chunk} w[b][v] * T2[v][e] ========
#define OCH 98     // ceil(50000/512)
__global__ __launch_bounds__(256) void oaccv_kernel(
    const float* __restrict__ emb, const float* __restrict__ w,
    float* __restrict__ o_part)          // [512][B][E]
{
    __shared__ float embS[64*128];   // 32 KB
    __shared__ float wS[64*32];      // 8 KB
    int t = threadIdx.x;
    int bg = t >> 6, lane = t & 63;
    int v0 = blockIdx.x * OCH;
    int vend = min(v0 + OCH, VV);
    float acc[8][2];
    #pragma unroll
    for (int j = 0; j < 8; j++) { acc[j][0] = 0.f; acc[j][1] = 0.f; }

    for (int vs = v0; vs < vend; vs += 64) {
        int nv = vend - vs; if (nv > 64) nv = 64;
        __syncthreads();
        for (int i = t; i < 64*32; i += 256) {
            int rowi = i >> 5, c4 = i & 31;
            float4 val = make_float4(0.f,0.f,0.f,0.f);
            if (rowi < nv) val = *(const float4*)(emb + (size_t)(vs+rowi)*EE + c4*4);
            *(float4*)(embS + rowi*128 + c4*4) = val;
        }
        for (int i = t; i < 512; i += 256) {
            int b = i >> 4, vv4 = (i & 15)*4;
            float4 val = make_float4(0.f,0.f,0.f,0.f);
            if (vv4 < nv) val = *(const float4*)(w + (size_t)b*VV + vs + vv4);
            wS[(vv4+0)*32 + b] = val.x;
            wS[(vv4+1)*32 + b] = val.y;
            wS[(vv4+2)*32 + b] = val.z;
            wS[(vv4+3)*32 + b] = val.w;
        }
        __syncthreads();
        for (int vv = 0; vv < nv; vv++) {
            float2 ev  = *(const float2*)(embS + vv*128 + lane*2);
            float4 w0v = *(const float4*)(wS + vv*32 + bg*8);       // uniform
            float4 w1v = *(const float4*)(wS + vv*32 + bg*8 + 4);   // uniform
            acc[0][0] += w0v.x*ev.x; acc[0][1] += w0v.x*ev.y;
            acc[1][0] += w0v.y*ev.x; acc[1][1] += w0v.y*ev.y;
            acc[2][0] += w0v.z*ev.x; acc[2][1] += w0v.z*ev.y;
            acc[3][0] += w0v.w*ev.x; acc[3][1] += w0v.w*ev.y;
            acc[4][0] += w1v.x*ev.x; acc[4][1] += w1v.x*ev.y;
            acc[5][0] += w1v.y*ev.x; acc[5][1] += w1v.y*ev.y;
            acc[6][0] += w1v.z*ev.x; acc[6][1] += w1v.z*ev.y;
            acc[7][0] += w1v.w*ev.x; acc[7][1] += w1v.w*ev.y;
        }
    }
    float* op = o_part + (size_t)blockIdx.x*BB*EE;
    #pragma unroll
    for (int j = 0; j < 8; j++) {
        float2 r; r.x = acc[j][0]; r.y = acc[j][1];
        *(float2*)(op + (bg*8+j)*EE + lane*2) = r;
    }
}

// ============ o_acc[i] = sum over 512 chunks of o_part ============
__global__ __launch_bounds__(256) void qupd_kernel(
    const float* __restrict__ o_part,    // [512][B*E]
    float* __restrict__ o_acc)           // [B*E]
{
    int i0 = blockIdx.x * 64;            // 64 blocks cover B*E=4096
    int sq = threadIdx.x >> 6;
    int il = threadIdx.x & 63;
    float v = 0.f;
    for (int s = sq; s < 512; s += 4)
        v += o_part[(size_t)s*BB*EE + i0 + il];
    __shared__ float red[4][64];
    red[sq][il] = v;
    __syncthreads();
    if (threadIdx.x < 64)
        o_acc[i0 + threadIdx.x] = red[0][threadIdx.x] + red[1][threadIdx.x]
                                + red[2][threadIdx.x] + red[3][threadIdx.x];
}

// ============ logits[b][v] = [h, o1] . Wv[v] + bv[v]   thread-owns-row ============
__global__ __launch_bounds__(256) void logits_kernel(
    const float* __restrict__ q0, const float* __restrict__ o1,
    const float* __restrict__ Wv, const float* __restrict__ bv,
    float* __restrict__ logits)
{
    __shared__ float u2[8192];   // 32 KB: [c 0..63][b][j]
    int t = threadIdx.x;
    for (int i = t; i < 8192; i += 256) {
        int e = i >> 5, b = i & 31;
        float v = (e < GG) ? q0[b*GG + e] : o1[b*EE + (e - GG)];
        u2[(e >> 2)*128 + b*4 + (e & 3)] = v;
    }
    __syncthreads();
    int lane = t & 63, bg = t >> 6;
    int v = blockIdx.x*64 + lane;
    const float4* row = (const float4*)(Wv + (size_t)(v < VV ? v : VV-1)*256);
    float acc[8];
    #pragma unroll
    for (int k = 0; k < 8; k++) acc[k] = 0.f;
    #pragma unroll 4
    for (int c = 0; c < 64; c++) {
        float4 wv = row[c];
        const float4* uq = (const float4*)(u2 + c*128 + bg*32);
        #pragma unroll
        for (int k = 0; k < 8; k++) {
            float4 u = uq[k];
            acc[k] += wv.x*u.x + wv.y*u.y + wv.z*u.z + wv.w*u.w;
        }
    }
    if (v < VV) {
        float bb = bv[v];
        #pragma unroll
        for (int k = 0; k < 8; k++)
            logits[(size_t)(bg*8 + k)*VV + v] = acc[k] + bb;
    }
}

// ============ vocab softmax partials ============
#define VCHUNK 6250
__global__ __launch_bounds__(256) void vpart_kernel(
    const float* __restrict__ logits, float* __restrict__ part)
{
    int blk = blockIdx.x;
    int b = blk >> 3, c = blk & 7;
    int t = threadIdx.x;
    const float* row = logits + (size_t)b*VV;
    int start = c*VCHUNK, end = min(start + VCHUNK, VV);
    __shared__ float red[8];
    int w = t >> 6, lane = t & 63;
    float mx = -INFINITY;
    for (int i = start + t; i < end; i += 256) mx = fmaxf(mx, row[i]);
    #pragma unroll
    for (int off = 32; off; off >>= 1) mx = fmaxf(mx, __shfl_down(mx, off));
    if (lane == 0) red[w] = mx;
    __syncthreads();
    float m = fmaxf(fmaxf(red[0], red[1]), fmaxf(red[2], red[3]));
    float sum = 0.f;
    for (int i = start + t; i < end; i += 256) sum += __expf(row[i] - m);
    #pragma unroll
    for (int off = 32; off; off >>= 1) sum += __shfl_down(sum, off);
    __syncthreads();
    if (lane == 0) red[4 + w] = sum;
    __syncthreads();
    if (t == 0) {
        part[blk*2]   = m;
        part[blk*2+1] = red[4]+red[5]+red[6]+red[7];
    }
}

// ============ finalize p_vocab in place ============
__global__ __launch_bounds__(256) void vfinal_kernel(
    float* __restrict__ logits, const float* __restrict__ part)
{
    int i = blockIdx.x*256 + threadIdx.x;
    if (i >= BB*VV) return;
    int b = i / VV;
    const float* pp = part + b*16;
    float M = -INFINITY;
    #pragma unroll
    for (int c = 0; c < 8; c++) M = fmaxf(M, pp[c*2]);
    float S = 0.f;
    #pragma unroll
    for (int c = 0; c < 8; c++) S += pp[c*2+1] * __expf(pp[c*2] - M);
    logits[i] = __expf(logits[i] - M) * (1.f / S);
}

extern "C" void kernel_launch(void* const* d_in, const int* in_sizes, int n_in,
                              void* d_out, int out_size, void* d_ws, size_t ws_size,
                              hipStream_t stream) {
    const int*   ctx    = (const int*)  d_in[0];
    const float* h_prev = (const float*)d_in[1];
    const int*   y      = (const int*)  d_in[2];
    const float* emb    = (const float*)d_in[3];
    const float* W_ih   = (const float*)d_in[4];
    const float* W_hh   = (const float*)d_in[5];
    const float* b_ih   = (const float*)d_in[6];
    const float* b_hh   = (const float*)d_in[7];
    const float* Wv     = (const float*)d_in[8];
    const float* bv     = (const float*)d_in[9];

    float* out_h    = (float*)d_out;
    float* out_pv   = out_h + BB*GG;
    float* out_attn = out_pv + (size_t)BB*VV;

    float* ws     = (float*)d_ws;
    float* q0     = ws;                        // 4096
    float* oa0    = q0 + BB*EE;                // 4096  (== o1)
    float* oa1    = oa0 + BB*EE;               // 4096
    float* part   = oa1 + BB*EE;               // 512
    float* p      = part + 512;                // B*M = 65536
    float* dbuf   = p + BB*MM;                 // B*V
    float* w0     = dbuf + (size_t)BB*VV;      // B*V (w0,w1 contiguous)
    float* w1     = w0 + (size_t)BB*VV;        // B*V
    float* o_part = w1 + (size_t)BB*VV;        // 512*B*E = 2M floats

    const int row_grid = (VV + 63)/64;         // 782

    gru_zero_kernel<<<BB + 256, 256, 0, stream>>>(emb, y, h_prev, W_ih, W_hh,
                                                  b_ih, b_hh, out_h, q0, w0);

    for (int hop = 0; hop < HOPS; hop++) {
        const float* embA = emb + (size_t)hop*VV*EE;
        int last = (hop == HOPS-1);
        dvec_kernel<<<row_grid, 256, 0, stream>>>(q0, oa0, oa1, hop, embA, dbuf);
        pgather_kernel<<<(BB*MM)/256, 256, 0, stream>>>(dbuf, ctx, p);
        float* wdst = (hop == 0) ? w0 : w1;
        softmax_sc_kernel<<<BB, 256, 0, stream>>>(p, ctx, wdst, out_attn, last);
        if (last) break;
        const float* embC = emb + (size_t)(hop+1)*VV*EE;
        oaccv_kernel<<<512, 256, 0, stream>>>(embC, wdst, o_part);
        qupd_kernel<<<(BB*EE)/64, 256, 0, stream>>>(o_part, hop == 0 ? oa0 : oa1);
    }

    logits_kernel<<<row_grid, 256, 0, stream>>>(q0, oa0, Wv, bv, out_pv);
    vpart_kernel<<<BB*8, 256, 0, stream>>>(out_pv, part);
    vfinal_kernel<<<(BB*VV + 255)/256, 256, 0, stream>>>(out_pv, part);
}